// Round 1
// baseline (142.280 us; speedup 1.0000x reference)
//
#include <hip/hip_runtime.h>

#define D_DIM 256
#define N_CLS 100

// ---------------- Kernel 1: histogram + serial scan (single block) ----------------
__global__ void k_hist_scan(const int* __restrict__ targets, int n,
                            int* __restrict__ offsets, int* __restrict__ cursor,
                            long long* __restrict__ npairs) {
    __shared__ int h[N_CLS];
    int t = threadIdx.x;
    if (t < N_CLS) h[t] = 0;
    __syncthreads();
    for (int i = t; i < n; i += blockDim.x)
        atomicAdd(&h[targets[i]], 1);
    __syncthreads();
    if (t == 0) {
        int acc = 0;
        long long p = 0;
        offsets[0] = 0;
        for (int c = 0; c < N_CLS; ++c) {
            int m = h[c];
            acc += m;
            offsets[c + 1] = acc;
            p += (long long)m * (m - 1) / 2;
        }
        *npairs = p;
    }
    if (t < N_CLS) cursor[t] = 0;
}

// ---------------- Kernel 2: scatter indices into class buckets ----------------
__global__ void k_scatter(const int* __restrict__ targets, int n,
                          const int* __restrict__ offsets, int* __restrict__ cursor,
                          int* __restrict__ bucket, int* __restrict__ endpos) {
    int i = blockIdx.x * blockDim.x + threadIdx.x;
    if (i < n) {
        int c = targets[i];
        int r = atomicAdd(&cursor[c], 1);
        int pos = offsets[c] + r;
        bucket[pos] = i;
        endpos[pos] = offsets[c + 1];
    }
}

// ---------------- Kernel 3: wave-per-row pairwise distance sums ----------------
// One 64-lane wave handles bucket position p: row i stays in registers (float4 per
// lane), loop over later positions in the same class segment. Coalesced 1KB row
// loads; 64-lane butterfly reduce; per-block double partial (no hot atomics).
__global__ __launch_bounds__(256) void k_pairs(const float* __restrict__ pred,
                                               const int* __restrict__ bucket,
                                               const int* __restrict__ endpos,
                                               int n, double* __restrict__ partials) {
    const int wave = (int)((blockIdx.x * blockDim.x + threadIdx.x) >> 6);
    const int lane = threadIdx.x & 63;
    const int wib  = threadIdx.x >> 6;

    float acc = 0.f;
    if (wave < n) {
        const int p = wave;
        const int i = bucket[p];
        const int e = endpos[p];
        const float4* rowi = (const float4*)(pred + (size_t)i * D_DIM);
        float4 a = rowi[lane];
        for (int q = p + 1; q < e; ++q) {
            int j = bucket[q];
            const float4* rowj = (const float4*)(pred + (size_t)j * D_DIM);
            float4 b = rowj[lane];
            float dx = a.x - b.x;
            float dy = a.y - b.y;
            float dz = a.z - b.z;
            float dw = a.w - b.w;
            float s = dx * dx + dy * dy + dz * dz + dw * dw;
            #pragma unroll
            for (int off = 32; off > 0; off >>= 1)
                s += __shfl_xor(s, off, 64);
            acc += sqrtf(s);   // all lanes hold full sum; redundant but harmless
        }
    }

    __shared__ float wsum[4];
    if (lane == 0) wsum[wib] = acc;
    __syncthreads();
    if (threadIdx.x == 0) {
        double tot = (double)wsum[0] + (double)wsum[1] + (double)wsum[2] + (double)wsum[3];
        partials[blockIdx.x] = tot;
    }
}

// ---------------- Kernel 4: reduce partials, divide by pair count ----------------
__global__ void k_final(const double* __restrict__ partials, int nblk,
                        const long long* __restrict__ npairs, float* __restrict__ out) {
    __shared__ double sh[256];
    int t = threadIdx.x;
    double s = 0.0;
    for (int idx = t; idx < nblk; idx += 256)
        s += partials[idx];
    sh[t] = s;
    __syncthreads();
    for (int w = 128; w > 0; w >>= 1) {
        if (t < w) sh[t] += sh[t + w];
        __syncthreads();
    }
    if (t == 0)
        out[0] = (float)(sh[0] / (double)(*npairs));
}

extern "C" void kernel_launch(void* const* d_in, const int* in_sizes, int n_in,
                              void* d_out, int out_size, void* d_ws, size_t ws_size,
                              hipStream_t stream) {
    const float* pred   = (const float*)d_in[0];
    const int* targets  = (const int*)d_in[1];
    float* out          = (float*)d_out;
    const int n = in_sizes[1];                 // 8192 rows

    // ws layout (all freshly written every call — ws is re-poisoned to 0xAA)
    char* ws = (char*)d_ws;
    const int nblk_pairs = (n * 64 + 255) / 256;          // 2048 for n=8192
    double*    partials = (double*)(ws);                   // nblk_pairs doubles
    size_t off = (size_t)nblk_pairs * sizeof(double);
    long long* npairs   = (long long*)(ws + off);  off += 8;
    int*       offsets  = (int*)(ws + off);        off += (N_CLS + 1) * sizeof(int);
    int*       cursor   = (int*)(ws + off);        off += N_CLS * sizeof(int);
    int*       bucket   = (int*)(ws + off);        off += (size_t)n * sizeof(int);
    int*       endpos   = (int*)(ws + off);        off += (size_t)n * sizeof(int);

    k_hist_scan<<<1, 1024, 0, stream>>>(targets, n, offsets, cursor, npairs);
    k_scatter<<<(n + 255) / 256, 256, 0, stream>>>(targets, n, offsets, cursor, bucket, endpos);
    k_pairs<<<nblk_pairs, 256, 0, stream>>>(pred, bucket, endpos, n, partials);
    k_final<<<1, 256, 0, stream>>>(partials, nblk_pairs, npairs, out);
}

// Round 2
// 116.854 us; speedup vs baseline: 1.2176x; 1.2176x over previous
//
#include <hip/hip_runtime.h>

#define N_CLS 100
#define D_DIM 256
#define D_CHUNKS 64          // float4 chunks per row
#define TILE 31              // rows per tile side
#define ROW_STRIDE 260       // floats; 260=4*65 -> 16B-aligned rows, bank group (row+chunk)%8
#define LDS_ROWS 63          // A rows 0..30 (row31 aliases), B rows 31..61, row 62 = garbage pad
#define NB_PAIRS 512
#define MAX_DESC 40960

// ---------- Kernel 1: histogram + offsets + tile descriptors + scatter (1 block) ----------
__global__ void k_prep(const int* __restrict__ targets, int n,
                       int* __restrict__ offsets,      // [N_CLS+1]
                       int* __restrict__ bucket,       // [n]
                       int2* __restrict__ descs,       // [MAX_DESC] (class, ti<<16|tj)
                       int* __restrict__ ntiles,       // [1]
                       long long* __restrict__ npairs) {
    __shared__ int h[N_CLS];
    __shared__ int cur[N_CLS];
    __shared__ int offs_s[N_CLS + 1];
    __shared__ int toff[N_CLS];
    int t = threadIdx.x;
    if (t < N_CLS) h[t] = 0;
    __syncthreads();
    for (int i = t; i < n; i += blockDim.x) atomicAdd(&h[targets[i]], 1);
    __syncthreads();
    if (t == 0) {
        int acc = 0; long long p = 0; int ta = 0;
        offs_s[0] = 0;
        for (int c = 0; c < N_CLS; ++c) {
            int m = h[c];
            acc += m; offs_s[c + 1] = acc;
            p += (long long)m * (m - 1) / 2;
            int k = (m + TILE - 1) / TILE;
            toff[c] = ta; ta += k * (k + 1) / 2;
        }
        *ntiles = ta; *npairs = p;
    }
    __syncthreads();
    if (t < N_CLS + 1) offsets[t] = offs_s[t];
    if (t < N_CLS) {
        int m = h[t];
        int k = (m + TILE - 1) / TILE;
        int idx = toff[t];
        for (int ti = 0; ti < k; ++ti)
            for (int tj = ti; tj < k; ++tj)
                descs[idx++] = make_int2(t, (ti << 16) | tj);
        cur[t] = offs_s[t];
    }
    __syncthreads();
    for (int i = t; i < n; i += blockDim.x) {
        int c = targets[i];
        int pos = atomicAdd(&cur[c], 1);
        bucket[pos] = i;
    }
}

// ---------- Kernel 2: tiled pairwise distances, thread-per-pair (2x2), LDS staging ----------
#define ACC4(S, A, B) { float dx=(A).x-(B).x, dy=(A).y-(B).y, dz=(A).z-(B).z, dw=(A).w-(B).w; \
  (S).x = fmaf(dx,dx,(S).x); (S).y = fmaf(dy,dy,(S).y); (S).z = fmaf(dz,dz,(S).z); (S).w = fmaf(dw,dw,(S).w); }

__global__ __launch_bounds__(256) void k_pairs(const float* __restrict__ pred,
        const int* __restrict__ bucket, const int* __restrict__ offsets,
        const int2* __restrict__ descs, const int* __restrict__ ntiles,
        double* __restrict__ partials) {
    __shared__ float lds[LDS_ROWS * ROW_STRIDE];   // 65520 B
    const int t = threadIdx.x;
    const int nt = *ntiles;
    const int ai = t >> 4;      // 0..15 -> a-rows {ai, ai+16}
    const int bj = t & 15;      // 0..15 -> b-rows {bj, bj+16}
    float acc = 0.0f;

    for (int d = blockIdx.x; d < nt; d += gridDim.x) {
        const int2 dsc = descs[d];
        const int c = dsc.x, ti = dsc.y >> 16, tj = dsc.y & 0xffff;
        const int base = offsets[c];
        const int m = offsets[c + 1] - base;
        const int ra0 = ti * TILE, rb0 = tj * TILE;

        __syncthreads();   // previous iteration's readers done before overwrite
        // stage 62 rows: lds rows 0..30 = A tile, 31..61 = B tile
        {
            const int cc = t & 63;
            for (int rr = (t >> 6); rr < 62; rr += 4) {
                int cls_pos = (rr < 31) ? (ra0 + rr) : (rb0 + rr - 31);
                if (cls_pos < m) {
                    int j = bucket[base + cls_pos];
                    float4 v = ((const float4*)(pred + (size_t)j * D_DIM))[cc];
                    *(float4*)(lds + rr * ROW_STRIDE + cc * 4) = v;
                }
            }
        }
        __syncthreads();

        const float4* Ap0 = (const float4*)(lds + ai * ROW_STRIDE);
        const float4* Ap1 = (const float4*)(lds + (ai + 16) * ROW_STRIDE);       // ai=15 -> garbage row, masked
        const float4* Bp0 = (const float4*)(lds + (31 + bj) * ROW_STRIDE);
        const float4* Bp1 = (const float4*)(lds + (31 + bj + 16) * ROW_STRIDE);  // bj=15 -> garbage row, masked
        float4 s00 = {0,0,0,0}, s01 = {0,0,0,0}, s10 = {0,0,0,0}, s11 = {0,0,0,0};
        #pragma unroll 4
        for (int k = 0; k < D_CHUNKS; ++k) {
            float4 a0 = Ap0[k], a1 = Ap1[k], b0 = Bp0[k], b1 = Bp1[k];
            ACC4(s00, a0, b0); ACC4(s01, a0, b1);
            ACC4(s10, a1, b0); ACC4(s11, a1, b1);
        }
        const int pa0 = ra0 + ai, pa1 = ra0 + ai + 16;
        const int pb0 = rb0 + bj, pb1 = rb0 + bj + 16;
        float r00 = (s00.x + s00.y) + (s00.z + s00.w);
        float r01 = (s01.x + s01.y) + (s01.z + s01.w);
        float r10 = (s10.x + s10.y) + (s10.z + s10.w);
        float r11 = (s11.x + s11.y) + (s11.z + s11.w);
        acc += (pb0 < m && pa0 < pb0) ? sqrtf(r00) : 0.0f;
        acc += (bj < 15 && pb1 < m && pa0 < pb1) ? sqrtf(r01) : 0.0f;
        acc += (ai < 15 && pb0 < m && pa1 < pb0) ? sqrtf(r10) : 0.0f;
        acc += (ai < 15 && bj < 15 && pb1 < m && pa1 < pb1) ? sqrtf(r11) : 0.0f;
    }

    // block reduction: wave shuffle -> lds -> thread 0
    #pragma unroll
    for (int off = 32; off; off >>= 1) acc += __shfl_xor(acc, off, 64);
    __syncthreads();
    if ((t & 63) == 0) lds[t >> 6] = acc;
    __syncthreads();
    if (t == 0)
        partials[blockIdx.x] = (double)lds[0] + (double)lds[1] + (double)lds[2] + (double)lds[3];
}

// ---------- Kernel 3: reduce 512 partials, divide ----------
__global__ void k_final(const double* __restrict__ partials,
                        const long long* __restrict__ npairs, float* __restrict__ out) {
    __shared__ double sh[256];
    int t = threadIdx.x;
    sh[t] = partials[t] + partials[t + 256];
    __syncthreads();
    for (int w = 128; w; w >>= 1) {
        if (t < w) sh[t] += sh[t + w];
        __syncthreads();
    }
    if (t == 0) out[0] = (float)(sh[0] / (double)(*npairs));
}

extern "C" void kernel_launch(void* const* d_in, const int* in_sizes, int n_in,
                              void* d_out, int out_size, void* d_ws, size_t ws_size,
                              hipStream_t stream) {
    const float* pred  = (const float*)d_in[0];
    const int* targets = (const int*)d_in[1];
    float* out         = (float*)d_out;
    const int n = in_sizes[1];     // 8192

    char* ws = (char*)d_ws;
    double*    partials = (double*)ws;                       // 512 * 8 = 4096 B
    long long* npairs   = (long long*)(ws + 4096);           // 8 B
    int2*      descs    = (int2*)(ws + 4104);                // MAX_DESC * 8 B
    size_t off = 4104 + (size_t)MAX_DESC * 8;
    int*       offsets  = (int*)(ws + off);  off += (N_CLS + 1) * sizeof(int);
    int*       ntiles   = (int*)(ws + off);  off += sizeof(int);
    int*       bucket   = (int*)(ws + off);

    k_prep<<<1, 256, 0, stream>>>(targets, n, offsets, bucket, descs, ntiles, npairs);
    k_pairs<<<NB_PAIRS, 256, 0, stream>>>(pred, bucket, offsets, descs, ntiles, partials);
    k_final<<<1, 256, 0, stream>>>(partials, npairs, out);
}

// Round 3
// 111.936 us; speedup vs baseline: 1.2711x; 1.0439x over previous
//
#include <hip/hip_runtime.h>

#define N_CLS 100
#define D_DIM 256
#define D_CHUNKS 64          // float4 chunks per row
#define TILE 31              // rows per tile side
#define ROW_STRIDE 260       // floats; bank group (row*260)%32 = 4*row%32 -> conflict-free
#define LDS_ROWS 63          // A rows 0..30, B rows 31..61, row 62 pad
#define NB_PAIRS 512
#define NB_HIST 32
#define MAX_DESC 40960

// ---------- Kernel A: per-block partial histograms (no global atomics) ----------
__global__ __launch_bounds__(256) void k_hist(const int* __restrict__ targets, int n,
                                              int* __restrict__ hist_part /*[NB_HIST*N_CLS]*/) {
    __shared__ int h[N_CLS];
    int t = threadIdx.x;
    if (t < N_CLS) h[t] = 0;
    __syncthreads();
    int i = blockIdx.x * blockDim.x + t;
    if (i < n) atomicAdd(&h[targets[i]], 1);
    __syncthreads();
    if (t < N_CLS) hist_part[blockIdx.x * N_CLS + t] = h[t];
}

// ---------- Kernel B: reduce hist, scan, gen descs, init cursors (1 tiny block) ----------
__global__ void k_scan_desc(const int* __restrict__ hist_part,
                            int* __restrict__ offsets,    // [N_CLS+1]
                            int* __restrict__ cursor,     // [N_CLS]
                            int2* __restrict__ descs,     // [MAX_DESC]
                            int* __restrict__ ntiles, long long* __restrict__ npairs) {
    __shared__ int h[N_CLS];
    __shared__ int offs_s[N_CLS + 1];
    __shared__ int toff[N_CLS];
    int t = threadIdx.x;
    if (t < N_CLS) {
        int s = 0;
        #pragma unroll
        for (int b = 0; b < NB_HIST; ++b) s += hist_part[b * N_CLS + t];
        h[t] = s;
    }
    __syncthreads();
    if (t == 0) {
        int acc = 0; long long p = 0; int ta = 0;
        offs_s[0] = 0;
        for (int c = 0; c < N_CLS; ++c) {
            int m = h[c];
            acc += m; offs_s[c + 1] = acc;
            p += (long long)m * (m - 1) / 2;
            int k = (m + TILE - 1) / TILE;
            toff[c] = ta; ta += k * (k + 1) / 2;
        }
        *ntiles = ta; *npairs = p;
    }
    __syncthreads();
    if (t < N_CLS + 1) offsets[t] = offs_s[t];
    if (t < N_CLS) {
        cursor[t] = offs_s[t];
        int m = h[t];
        int k = (m + TILE - 1) / TILE;
        int idx = toff[t];
        for (int ti = 0; ti < k; ++ti)
            for (int tj = ti; tj < k; ++tj)
                descs[idx++] = make_int2(t, (ti << 16) | tj);
    }
}

// ---------- Kernel C: scatter rows into class buckets (global atomic cursors) ----------
__global__ __launch_bounds__(256) void k_scatter(const int* __restrict__ targets, int n,
                                                 int* __restrict__ cursor,
                                                 int* __restrict__ bucket) {
    int i = blockIdx.x * blockDim.x + threadIdx.x;
    if (i < n) {
        int pos = atomicAdd(&cursor[targets[i]], 1);
        bucket[pos] = i;
    }
}

// ---------- Kernel D: tiled pairwise distances, thread-per-2x2-pairs, LDS staging ----------
#define ACC4(S, A, B) { float dx=(A).x-(B).x, dy=(A).y-(B).y, dz=(A).z-(B).z, dw=(A).w-(B).w; \
  (S).x = fmaf(dx,dx,(S).x); (S).y = fmaf(dy,dy,(S).y); (S).z = fmaf(dz,dz,(S).z); (S).w = fmaf(dw,dw,(S).w); }

__global__ __launch_bounds__(256) void k_pairs(const float* __restrict__ pred,
        const int* __restrict__ bucket, const int* __restrict__ offsets,
        const int2* __restrict__ descs, const int* __restrict__ ntiles,
        double* __restrict__ partials) {
    __shared__ float lds[LDS_ROWS * ROW_STRIDE];   // 65520 B -> 2 blocks/CU
    const int t = threadIdx.x;
    const int nt = *ntiles;
    const int ai = t >> 4;      // 0..15 -> a-rows {ai, ai+16}
    const int bj = t & 15;      // 0..15 -> b-rows {bj, bj+16}
    float acc = 0.0f;

    for (int d = blockIdx.x; d < nt; d += gridDim.x) {
        const int2 dsc = descs[d];
        const int c = dsc.x, ti = dsc.y >> 16, tj = dsc.y & 0xffff;
        const int base = offsets[c];
        const int m = offsets[c + 1] - base;
        const int ra0 = ti * TILE, rb0 = tj * TILE;

        __syncthreads();   // prev readers done before overwrite
        {
            const int cc = t & 63;
            for (int rr = (t >> 6); rr < 62; rr += 4) {
                int cls_pos = (rr < 31) ? (ra0 + rr) : (rb0 + rr - 31);
                if (cls_pos < m) {
                    int j = bucket[base + cls_pos];
                    float4 v = ((const float4*)(pred + (size_t)j * D_DIM))[cc];
                    *(float4*)(lds + rr * ROW_STRIDE + cc * 4) = v;
                }
            }
        }
        __syncthreads();

        const float4* Ap0 = (const float4*)(lds + ai * ROW_STRIDE);
        const float4* Ap1 = (const float4*)(lds + (ai + 16) * ROW_STRIDE);       // ai=15 masked
        const float4* Bp0 = (const float4*)(lds + (31 + bj) * ROW_STRIDE);
        const float4* Bp1 = (const float4*)(lds + (31 + bj + 16) * ROW_STRIDE);  // bj=15 masked
        float4 s00 = {0,0,0,0}, s01 = {0,0,0,0}, s10 = {0,0,0,0}, s11 = {0,0,0,0};
        #pragma unroll 4
        for (int k = 0; k < D_CHUNKS; ++k) {
            float4 a0 = Ap0[k], a1 = Ap1[k], b0 = Bp0[k], b1 = Bp1[k];
            ACC4(s00, a0, b0); ACC4(s01, a0, b1);
            ACC4(s10, a1, b0); ACC4(s11, a1, b1);
        }
        const int pa0 = ra0 + ai, pa1 = ra0 + ai + 16;
        const int pb0 = rb0 + bj, pb1 = rb0 + bj + 16;
        float r00 = (s00.x + s00.y) + (s00.z + s00.w);
        float r01 = (s01.x + s01.y) + (s01.z + s01.w);
        float r10 = (s10.x + s10.y) + (s10.z + s10.w);
        float r11 = (s11.x + s11.y) + (s11.z + s11.w);
        acc += (pb0 < m && pa0 < pb0) ? sqrtf(r00) : 0.0f;
        acc += (bj < 15 && pb1 < m && pa0 < pb1) ? sqrtf(r01) : 0.0f;
        acc += (ai < 15 && pb0 < m && pa1 < pb0) ? sqrtf(r10) : 0.0f;
        acc += (ai < 15 && bj < 15 && pb1 < m && pa1 < pb1) ? sqrtf(r11) : 0.0f;
    }

    #pragma unroll
    for (int off = 32; off; off >>= 1) acc += __shfl_xor(acc, off, 64);
    __syncthreads();
    if ((t & 63) == 0) lds[t >> 6] = acc;
    __syncthreads();
    if (t == 0)
        partials[blockIdx.x] = (double)lds[0] + (double)lds[1] + (double)lds[2] + (double)lds[3];
}

// ---------- Kernel E: reduce partials, divide ----------
__global__ void k_final(const double* __restrict__ partials,
                        const long long* __restrict__ npairs, float* __restrict__ out) {
    __shared__ double sh[256];
    int t = threadIdx.x;
    sh[t] = partials[t] + partials[t + 256];
    __syncthreads();
    for (int w = 128; w; w >>= 1) {
        if (t < w) sh[t] += sh[t + w];
        __syncthreads();
    }
    if (t == 0) out[0] = (float)(sh[0] / (double)(*npairs));
}

extern "C" void kernel_launch(void* const* d_in, const int* in_sizes, int n_in,
                              void* d_out, int out_size, void* d_ws, size_t ws_size,
                              hipStream_t stream) {
    const float* pred  = (const float*)d_in[0];
    const int* targets = (const int*)d_in[1];
    float* out         = (float*)d_out;
    const int n = in_sizes[1];     // 8192

    char* ws = (char*)d_ws;
    size_t off = 0;
    double*    partials  = (double*)(ws + off);    off += (size_t)NB_PAIRS * 8;
    long long* npairs    = (long long*)(ws + off); off += 8;
    int2*      descs     = (int2*)(ws + off);      off += (size_t)MAX_DESC * 8;
    int*       hist_part = (int*)(ws + off);       off += (size_t)NB_HIST * N_CLS * 4;
    int*       offsets   = (int*)(ws + off);       off += (N_CLS + 1) * 4;
    int*       cursor    = (int*)(ws + off);       off += N_CLS * 4;
    int*       ntiles    = (int*)(ws + off);       off += 4;
    int*       bucket    = (int*)(ws + off);

    k_hist<<<NB_HIST, 256, 0, stream>>>(targets, n, hist_part);
    k_scan_desc<<<1, 128, 0, stream>>>(hist_part, offsets, cursor, descs, ntiles, npairs);
    k_scatter<<<(n + 255) / 256, 256, 0, stream>>>(targets, n, cursor, bucket);
    k_pairs<<<NB_PAIRS, 256, 0, stream>>>(pred, bucket, offsets, descs, ntiles, partials);
    k_final<<<1, 256, 0, stream>>>(partials, npairs, out);
}

// Round 4
// 97.100 us; speedup vs baseline: 1.4653x; 1.1528x over previous
//
#include <hip/hip_runtime.h>

#define N_CLS 100
#define D_DIM 256
#define TILE 32              // rows per Gram tile side
#define NB_HIST 32
#define NB_GRAM 1024
#define MAX_DESC 8192
#define ROW_SH 264           // shorts per LDS row = 528 B = 33*16 -> 16B-aligned, 2-way banks only

typedef short bf16x8 __attribute__((ext_vector_type(8)));
typedef float f32x4  __attribute__((ext_vector_type(4)));

__device__ __forceinline__ unsigned short f2bf(float f) {   // fp32 -> bf16 RNE
    unsigned int b = __float_as_uint(f);
    return (unsigned short)((b + 0x7FFFu + ((b >> 16) & 1u)) >> 16);
}

// ---------- Kernel A: per-block partial histograms ----------
__global__ __launch_bounds__(256) void k_hist(const int* __restrict__ targets, int n,
                                              int* __restrict__ hist_part) {
    __shared__ int h[N_CLS];
    int t = threadIdx.x;
    if (t < N_CLS) h[t] = 0;
    __syncthreads();
    int i = blockIdx.x * blockDim.x + t;
    if (i < n) atomicAdd(&h[targets[i]], 1);
    __syncthreads();
    if (t < N_CLS) hist_part[blockIdx.x * N_CLS + t] = h[t];
}

// ---------- Kernel B: reduce hist, scan, gen 32x32-tile descs, init cursors ----------
__global__ void k_scan(const int* __restrict__ hist_part,
                       int* __restrict__ offsets, int* __restrict__ cursor,
                       int2* __restrict__ descs, int* __restrict__ ndesc,
                       long long* __restrict__ npairs) {
    __shared__ int h[N_CLS];
    __shared__ int offs_s[N_CLS + 1];
    __shared__ int toff[N_CLS];
    int t = threadIdx.x;
    if (t < N_CLS) {
        int s = 0;
        for (int b = 0; b < NB_HIST; ++b) s += hist_part[b * N_CLS + t];
        h[t] = s;
    }
    __syncthreads();
    if (t == 0) {
        int acc = 0; long long p = 0; int ta = 0;
        offs_s[0] = 0;
        for (int c = 0; c < N_CLS; ++c) {
            int m = h[c]; acc += m; offs_s[c + 1] = acc;
            p += (long long)m * (m - 1) / 2;
            int k = (m + TILE - 1) / TILE;
            toff[c] = ta; ta += k * (k + 1) / 2;
        }
        *ndesc = ta; *npairs = p;
    }
    __syncthreads();
    if (t <= N_CLS) offsets[t] = offs_s[t];
    if (t < N_CLS) {
        cursor[t] = offs_s[t];
        int k = (h[t] + TILE - 1) / TILE;
        int idx = toff[t];
        for (int ti = 0; ti < k; ++ti)
            for (int tj = ti; tj < k; ++tj)
                descs[idx++] = make_int2(t, (ti << 16) | tj);
    }
}

// ---------- Kernel C: scatter rows into class buckets ----------
__global__ __launch_bounds__(256) void k_scatter(const int* __restrict__ targets, int n,
                                                 int* __restrict__ cursor,
                                                 int* __restrict__ bucket) {
    int i = blockIdx.x * blockDim.x + threadIdx.x;
    if (i < n) {
        int pos = atomicAdd(&cursor[targets[i]], 1);
        bucket[pos] = i;
    }
}

// ---------- Kernel D: per-desc bf16 MFMA Gram + sqrt-sum epilogue ----------
// Block stages A-tile (32 rows) + B-tile (32 rows) as bf16 + exact fp32 sq per row.
// Wave w computes 16x16 tile (tA=w>>1, tB=w&1): 8x mfma_f32_16x16x32_bf16.
// d2 = sq_i + sq_j - 2*G_ij (sq exact fp32; only cross term bf16 -> loss err ~1e-4).
__global__ __launch_bounds__(256) void k_gram(const float* __restrict__ pred,
        const int* __restrict__ bucket, const int* __restrict__ offsets,
        const int2* __restrict__ descs, const int* __restrict__ ndesc_p,
        double* __restrict__ partials) {
    __shared__ alignas(16) short tileS[64 * ROW_SH];   // 33792 B
    __shared__ float sqs[64];
    __shared__ float wsum[4];
    const int t = threadIdx.x;
    const int lane = t & 63, wave = t >> 6;
    const int ndesc = *ndesc_p;
    float accum = 0.f;

    for (int d = blockIdx.x; d < ndesc; d += NB_GRAM) {
        const int2 dsc = descs[d];
        const int c = dsc.x, ti = dsc.y >> 16, tj = dsc.y & 0xffff;
        const int base = offsets[c];
        const int m = offsets[c + 1] - base;
        const int ra0 = ti * TILE, rb0 = tj * TILE;

        __syncthreads();   // prev iteration readers done
        // stage: wave per row, lane = float4 chunk; rows 0-31 = A, 32-63 = B
        for (int r = wave; r < 64; r += 4) {
            int cp = (r < 32) ? (ra0 + r) : (rb0 + r - 32);
            float4 v = make_float4(0.f, 0.f, 0.f, 0.f);
            if (cp < m) {
                int g = bucket[base + cp];
                v = ((const float4*)(pred + (size_t)g * D_DIM))[lane];
            }
            short4 pk;
            pk.x = (short)f2bf(v.x); pk.y = (short)f2bf(v.y);
            pk.z = (short)f2bf(v.z); pk.w = (short)f2bf(v.w);
            *(short4*)&tileS[r * ROW_SH + lane * 4] = pk;
            float s = v.x * v.x + v.y * v.y + v.z * v.z + v.w * v.w;
            #pragma unroll
            for (int o = 32; o; o >>= 1) s += __shfl_xor(s, o, 64);
            if (lane == 0) sqs[r] = s;   // exact fp32 ||row||^2
        }
        __syncthreads();

        // MFMA: wave's 16x16 tile of G = A x B^T
        const int tA = wave >> 1, tB = wave & 1;
        const int q = lane >> 4, l15 = lane & 15;
        const short* aP = &tileS[(tA * 16 + l15) * ROW_SH + q * 8];
        const short* bP = &tileS[(32 + tB * 16 + l15) * ROW_SH + q * 8];
        f32x4 acc = {0.f, 0.f, 0.f, 0.f};
        #pragma unroll
        for (int ks = 0; ks < 8; ++ks) {
            bf16x8 af = *(const bf16x8*)(aP + ks * 32);
            bf16x8 bg = *(const bf16x8*)(bP + ks * 32);
            acc = __builtin_amdgcn_mfma_f32_16x16x32_bf16(af, bg, acc, 0, 0, 0);
        }
        // epilogue: D row=(lane>>4)*4+reg -> i, col=lane&15 -> j
        #pragma unroll
        for (int rr = 0; rr < 4; ++rr) {
            int aloc = tA * 16 + q * 4 + rr;
            int bloc = tB * 16 + l15;
            int pi = ra0 + aloc, pj = rb0 + bloc;
            float d2 = sqs[aloc] + sqs[32 + bloc] - 2.f * acc[rr];
            if (pj < m && pi < pj) accum += sqrtf(fmaxf(d2, 0.f));
        }
    }

    float s = accum;
    #pragma unroll
    for (int o = 32; o; o >>= 1) s += __shfl_xor(s, o, 64);
    __syncthreads();
    if (lane == 0) wsum[wave] = s;
    __syncthreads();
    if (t == 0)
        partials[blockIdx.x] = (double)wsum[0] + (double)wsum[1] + (double)wsum[2] + (double)wsum[3];
}

// ---------- Kernel E: reduce partials, divide ----------
__global__ void k_final(const double* __restrict__ partials,
                        const long long* __restrict__ npairs, float* __restrict__ out) {
    __shared__ double sh[256];
    int t = threadIdx.x;
    double s = 0.0;
    for (int i = t; i < NB_GRAM; i += 256) s += partials[i];
    sh[t] = s;
    __syncthreads();
    for (int w = 128; w; w >>= 1) {
        if (t < w) sh[t] += sh[t + w];
        __syncthreads();
    }
    if (t == 0) out[0] = (float)(sh[0] / (double)(*npairs));
}

extern "C" void kernel_launch(void* const* d_in, const int* in_sizes, int n_in,
                              void* d_out, int out_size, void* d_ws, size_t ws_size,
                              hipStream_t stream) {
    const float* pred  = (const float*)d_in[0];
    const int* targets = (const int*)d_in[1];
    float* out         = (float*)d_out;
    const int n = in_sizes[1];     // 8192

    char* ws = (char*)d_ws;
    size_t off = 0;
    double*    partials  = (double*)(ws + off);    off += (size_t)NB_GRAM * 8;
    long long* npairs    = (long long*)(ws + off); off += 8;
    int2*      descs     = (int2*)(ws + off);      off += (size_t)MAX_DESC * 8;
    int*       hist_part = (int*)(ws + off);       off += (size_t)NB_HIST * N_CLS * 4;
    int*       offsets   = (int*)(ws + off);       off += (N_CLS + 1) * 4;
    int*       cursor    = (int*)(ws + off);       off += N_CLS * 4;
    int*       ndesc     = (int*)(ws + off);       off += 4;
    int*       bucket    = (int*)(ws + off);

    k_hist<<<NB_HIST, 256, 0, stream>>>(targets, n, hist_part);
    k_scan<<<1, 128, 0, stream>>>(hist_part, offsets, cursor, descs, ndesc, npairs);
    k_scatter<<<(n + 255) / 256, 256, 0, stream>>>(targets, n, cursor, bucket);
    k_gram<<<NB_GRAM, 256, 0, stream>>>(pred, bucket, offsets, descs, ndesc, partials);
    k_final<<<1, 256, 0, stream>>>(partials, npairs, out);
}

// Round 5
// 80.092 us; speedup vs baseline: 1.7765x; 1.2124x over previous
//
#include <hip/hip_runtime.h>

#define N_CLS 100
#define D_DIM 256
#define MAX_M 112            // fast-path row capacity (7 tiles of 16)
#define ROW_SH 264           // shorts per LDS row = 528 B: 16B-aligned, 2-way banks (free)
#define PANEL 48             // slow-path panel rows (3 tiles) — only if some m > 112

typedef short bf16x8 __attribute__((ext_vector_type(8)));
typedef float f32x4  __attribute__((ext_vector_type(4)));

__device__ __forceinline__ unsigned short f2bf(float f) {   // fp32 -> bf16 RNE
    unsigned int b = __float_as_uint(f);
    return (unsigned short)((b + 0x7FFFu + ((b >> 16) & 1u)) >> 16);
}

// ---------- Kernel 1: fused hist + scan + scatter + init (1 block, 1024 thr) ----------
__global__ __launch_bounds__(1024) void k_prep(const int* __restrict__ targets, int n,
        int* __restrict__ offsets, int* __restrict__ bucket,
        double* __restrict__ npairs, double* __restrict__ gsum, int* __restrict__ gcount) {
    __shared__ int h[N_CLS], cur[N_CLS], offs[N_CLS + 1];
    const int t = threadIdx.x;
    if (t < N_CLS) h[t] = 0;
    __syncthreads();
    for (int i = t; i < n; i += 1024) atomicAdd(&h[targets[i]], 1);
    __syncthreads();
    if (t == 0) {
        int acc = 0; double p = 0.0;
        offs[0] = 0;
        for (int c = 0; c < N_CLS; ++c) {
            int m = h[c]; acc += m; offs[c + 1] = acc;
            p += (double)m * (double)(m - 1) * 0.5;
        }
        *npairs = p; *gsum = 0.0; *gcount = 0;
    }
    __syncthreads();
    if (t <= N_CLS) offsets[t] = offs[t];
    if (t < N_CLS) cur[t] = offs[t];
    __syncthreads();
    for (int i = t; i < n; i += 1024) {
        int c = targets[i];
        int pos = atomicAdd(&cur[c], 1);   // LDS cursor; intra-class order irrelevant
        bucket[pos] = i;
    }
}

// ---------- helpers for kernel 2 ----------
// Stage cnt rows (class positions cp0..cp0+cnt) into LDS slots dslot.. as bf16,
// with exact-fp32 ||row||^2 into sqs. Wave-per-row, lane = float4 chunk.
__device__ __forceinline__ void stage(const float* __restrict__ pred,
        const int* __restrict__ bucket, int base, int m, int cp0, int dslot, int cnt,
        short* tileS, float* sqs, int wave, int lane) {
    for (int r = wave; r < cnt; r += 8) {
        int cp = cp0 + r;
        float4 v = make_float4(0.f, 0.f, 0.f, 0.f);
        if (cp < m) {                                  // wave-uniform branch
            int g = bucket[base + cp];                 // wave-uniform -> s_load
            v = ((const float4*)(pred + (size_t)g * D_DIM))[lane];
        }
        short4 pk;
        pk.x = (short)f2bf(v.x); pk.y = (short)f2bf(v.y);
        pk.z = (short)f2bf(v.z); pk.w = (short)f2bf(v.w);
        *(short4*)&tileS[(dslot + r) * ROW_SH + lane * 4] = pk;
        float s = v.x * v.x + v.y * v.y + v.z * v.z + v.w * v.w;
        #pragma unroll
        for (int o = 32; o; o >>= 1) s += __shfl_xor(s, o, 64);
        if (lane == 0) sqs[dslot + r] = s;
    }
}

// One 16x16 MFMA tile: A rows at slot a0.., B rows at slot b0..; global in-class
// positions ga0/gb0; returns this lane's masked sum of sqrt(d2).
// C/D layout (HW-verified): col=lane&15 -> B row, row=(lane>>4)*4+rr -> A row.
__device__ __forceinline__ float tile16(const short* tileS, const float* sqs,
        int a0, int b0, int ga0, int gb0, int m, int lane) {
    const int q = lane >> 4, l15 = lane & 15;
    const short* aP = &tileS[(a0 + l15) * ROW_SH + q * 8];
    const short* bP = &tileS[(b0 + l15) * ROW_SH + q * 8];
    f32x4 acc = {0.f, 0.f, 0.f, 0.f};
    #pragma unroll
    for (int ks = 0; ks < 8; ++ks) {
        bf16x8 af = *(const bf16x8*)(aP + ks * 32);
        bf16x8 bg = *(const bf16x8*)(bP + ks * 32);
        acc = __builtin_amdgcn_mfma_f32_16x16x32_bf16(af, bg, acc, 0, 0, 0);
    }
    float out = 0.f;
    #pragma unroll
    for (int rr = 0; rr < 4; ++rr) {
        int al = q * 4 + rr;
        int pi = ga0 + al, pj = gb0 + l15;
        float d2 = sqs[a0 + al] + sqs[b0 + l15] - 2.f * acc[rr];
        if (pj < m && pi < pj) out += sqrtf(fmaxf(d2, 0.f));
    }
    return out;
}

// ---------- Kernel 2: block-per-class Gram + sqrt-sum + fused finalize ----------
__global__ __launch_bounds__(512) void k_gram(const float* __restrict__ pred,
        const int* __restrict__ bucket, const int* __restrict__ offsets,
        const double* __restrict__ npairs, double* __restrict__ gsum,
        int* __restrict__ gcount, float* __restrict__ out) {
    __shared__ short tileS[MAX_M * ROW_SH];   // 59136 B
    __shared__ float sqs[MAX_M];
    __shared__ float wsum[8];
    const int t = threadIdx.x, lane = t & 63, wave = t >> 6;
    const int c = blockIdx.x;
    const int base = offsets[c];
    const int m = offsets[c + 1] - base;
    float accum = 0.f;

    if (m <= MAX_M) {
        // stage whole class once; waves grid-stride the tile-pair triangle
        const int T = (m + 15) >> 4;
        stage(pred, bucket, base, m, 0, 0, T * 16, tileS, sqs, wave, lane);
        __syncthreads();
        const int np = T * (T + 1) / 2;
        for (int idx = wave; idx < np; idx += 8) {
            int ta = 0, r = idx;
            while (r >= T - ta) { r -= T - ta; ++ta; }
            int tb = ta + r;
            accum += tile16(tileS, sqs, ta * 16, tb * 16, ta * 16, tb * 16, m, lane);
        }
    } else {
        // general fallback: 48-row panel pairs (correct for any m; ~never runs)
        const int P = (m + PANEL - 1) / PANEL;
        for (int pi = 0; pi < P; ++pi)
        for (int pj = pi; pj < P; ++pj) {
            __syncthreads();
            stage(pred, bucket, base, m, pi * PANEL, 0,     PANEL, tileS, sqs, wave, lane);
            stage(pred, bucket, base, m, pj * PANEL, PANEL, PANEL, tileS, sqs, wave, lane);
            __syncthreads();
            for (int idx = wave; idx < 9; idx += 8) {
                int ta = idx / 3, tb = idx % 3;
                accum += tile16(tileS, sqs, ta * 16, PANEL + tb * 16,
                                pi * PANEL + ta * 16, pj * PANEL + tb * 16, m, lane);
            }
        }
    }

    #pragma unroll
    for (int o = 32; o; o >>= 1) accum += __shfl_xor(accum, o, 64);
    if (lane == 0) wsum[wave] = accum;
    __syncthreads();
    if (t == 0) {
        double bs = 0.0;
        #pragma unroll
        for (int w = 0; w < 8; ++w) bs += (double)wsum[w];
        atomicAdd(gsum, bs);            // device-scope fp64 atomic
        __threadfence();
        int ticket = atomicAdd(gcount, 1);
        if (ticket == (int)gridDim.x - 1) {
            __threadfence();
            double s = atomicAdd(gsum, 0.0);   // coherent read after all adds
            out[0] = (float)(s / *npairs);
        }
    }
}

extern "C" void kernel_launch(void* const* d_in, const int* in_sizes, int n_in,
                              void* d_out, int out_size, void* d_ws, size_t ws_size,
                              hipStream_t stream) {
    const float* pred  = (const float*)d_in[0];
    const int* targets = (const int*)d_in[1];
    float* out         = (float*)d_out;
    const int n = in_sizes[1];     // 8192

    char* ws = (char*)d_ws;
    size_t off = 0;
    double* npairs  = (double*)(ws + off); off += 8;
    double* gsum    = (double*)(ws + off); off += 8;
    int*    gcount  = (int*)(ws + off);    off += 8;
    int*    offsets = (int*)(ws + off);    off += (N_CLS + 1) * 4;
    int*    bucket  = (int*)(ws + off);

    k_prep<<<1, 1024, 0, stream>>>(targets, n, offsets, bucket, npairs, gsum, gcount);
    k_gram<<<N_CLS, 512, 0, stream>>>(pred, bucket, offsets, npairs, gsum, gcount, out);
}

// Round 6
// 76.530 us; speedup vs baseline: 1.8591x; 1.0466x over previous
//
#include <hip/hip_runtime.h>

#define N_CLS 100
#define D_DIM 256
#define MAX_M 112            // fast-path row capacity (7 tiles of 16)
#define ROW_SH 264           // shorts per LDS row = 528 B: 16B-aligned, 2-way banks (free)
#define PANEL 48             // slow-path panel rows — only if some class m > 112

typedef short bf16x8 __attribute__((ext_vector_type(8)));
typedef float f32x4  __attribute__((ext_vector_type(4)));

__device__ __forceinline__ unsigned short f2bf(float f) {   // fp32 -> bf16 RNE
    unsigned int b = __float_as_uint(f);
    return (unsigned short)((b + 0x7FFFu + ((b >> 16) & 1u)) >> 16);
}

// Stage cnt rows (class positions cp0..) into LDS slots dslot.. as bf16 + exact
// fp32 ||row||^2. Wave-per-row, lane = float4 chunk. Rows >= m stage as zeros.
__device__ __forceinline__ void stage(const float* __restrict__ pred,
        const int* __restrict__ bkt, int m, int cp0, int dslot, int cnt,
        short* tileS, float* sqs, int wave, int lane) {
    for (int r = wave; r < cnt; r += 8) {
        int cp = cp0 + r;
        float4 v = make_float4(0.f, 0.f, 0.f, 0.f);
        if (cp < m) {                                  // wave-uniform branch
            int g = bkt[cp];                           // wave-uniform load
            v = ((const float4*)(pred + (size_t)g * D_DIM))[lane];
        }
        short4 pk;
        pk.x = (short)f2bf(v.x); pk.y = (short)f2bf(v.y);
        pk.z = (short)f2bf(v.z); pk.w = (short)f2bf(v.w);
        *(short4*)&tileS[(dslot + r) * ROW_SH + lane * 4] = pk;
        float s = v.x * v.x + v.y * v.y + v.z * v.z + v.w * v.w;
        #pragma unroll
        for (int o = 32; o; o >>= 1) s += __shfl_xor(s, o, 64);
        if (lane == 0) sqs[dslot + r] = s;
    }
}

// One 16x16 MFMA tile. C/D layout (HW-verified): col=lane&15 -> B row,
// row=(lane>>4)*4+rr -> A row. d2 = sq_i + sq_j - 2*G_ij.
__device__ __forceinline__ float tile16(const short* tileS, const float* sqs,
        int a0, int b0, int ga0, int gb0, int m, int lane) {
    const int q = lane >> 4, l15 = lane & 15;
    const short* aP = &tileS[(a0 + l15) * ROW_SH + q * 8];
    const short* bP = &tileS[(b0 + l15) * ROW_SH + q * 8];
    f32x4 acc = {0.f, 0.f, 0.f, 0.f};
    #pragma unroll
    for (int ks = 0; ks < 8; ++ks) {
        bf16x8 af = *(const bf16x8*)(aP + ks * 32);
        bf16x8 bg = *(const bf16x8*)(bP + ks * 32);
        acc = __builtin_amdgcn_mfma_f32_16x16x32_bf16(af, bg, acc, 0, 0, 0);
    }
    float out = 0.f;
    #pragma unroll
    for (int rr = 0; rr < 4; ++rr) {
        int al = q * 4 + rr;
        int pi = ga0 + al, pj = gb0 + l15;
        float d2 = sqs[a0 + al] + sqs[b0 + l15] - 2.f * acc[rr];
        if (pj < m && pi < pj) out += sqrtf(fmaxf(d2, 0.f));
    }
    return out;
}

// ---------- Kernel 1: self-contained block-per-class ----------
// Block c: compact its row indices from targets (order irrelevant), stage as
// bf16 to LDS, MFMA Gram triangle, store psum[c]/pcnt[c] via plain stores.
__global__ __launch_bounds__(512) void k_gram(const float* __restrict__ pred,
        const int* __restrict__ targets, int n, int* __restrict__ bucket_g,
        double* __restrict__ psum, double* __restrict__ pcnt) {
    __shared__ short tileS[MAX_M * ROW_SH];   // 59136 B
    __shared__ float sqs[MAX_M];
    __shared__ float wsum[8];
    __shared__ int cnt_s;
    const int t = threadIdx.x, lane = t & 63, wave = t >> 6;
    const int c = blockIdx.x;
    int* bkt = bucket_g + (size_t)c * n;      // private per-class region

    if (t == 0) cnt_s = 0;
    __syncthreads();
    for (int i = t; i < n; i += 512)
        if (targets[i] == c) bkt[atomicAdd(&cnt_s, 1)] = i;
    __syncthreads();                          // orders LDS cnt + global bkt writes
    const int m = cnt_s;
    float accum = 0.f;

    if (m <= MAX_M) {
        const int T = (m + 15) >> 4;          // 0 if m==0
        stage(pred, bkt, m, 0, 0, T * 16, tileS, sqs, wave, lane);
        __syncthreads();
        const int np = T * (T + 1) / 2;
        for (int idx = wave; idx < np; idx += 8) {
            int ta = 0, r = idx;
            while (r >= T - ta) { r -= T - ta; ++ta; }
            int tb = ta + r;
            accum += tile16(tileS, sqs, ta * 16, tb * 16, ta * 16, tb * 16, m, lane);
        }
    } else {
        // general fallback: 48-row panel pairs (correct for any m; ~never runs)
        const int P = (m + PANEL - 1) / PANEL;
        for (int pi = 0; pi < P; ++pi)
        for (int pj = pi; pj < P; ++pj) {
            __syncthreads();
            stage(pred, bkt, m, pi * PANEL, 0,     PANEL, tileS, sqs, wave, lane);
            stage(pred, bkt, m, pj * PANEL, PANEL, PANEL, tileS, sqs, wave, lane);
            __syncthreads();
            for (int idx = wave; idx < 9; idx += 8) {
                int ta = idx / 3, tb = idx % 3;
                accum += tile16(tileS, sqs, ta * 16, PANEL + tb * 16,
                                pi * PANEL + ta * 16, pj * PANEL + tb * 16, m, lane);
            }
        }
    }

    #pragma unroll
    for (int o = 32; o; o >>= 1) accum += __shfl_xor(accum, o, 64);
    if (lane == 0) wsum[wave] = accum;
    __syncthreads();
    if (t == 0) {
        double bs = 0.0;
        #pragma unroll
        for (int w = 0; w < 8; ++w) bs += (double)wsum[w];
        psum[c] = bs;                                      // plain stores, no init needed
        pcnt[c] = (double)m * (double)(m - 1) * 0.5;
    }
}

// ---------- Kernel 2: reduce 100 per-class partials, divide ----------
__global__ void k_final(const double* __restrict__ psum, const double* __restrict__ pcnt,
                        float* __restrict__ out) {
    __shared__ double sh[128], ch[128];
    int t = threadIdx.x;
    double s = (t < N_CLS) ? psum[t] : 0.0;
    double q = (t < N_CLS) ? pcnt[t] : 0.0;
    sh[t] = s; ch[t] = q;
    __syncthreads();
    for (int w = 64; w; w >>= 1) {
        if (t < w) { sh[t] += sh[t + w]; ch[t] += ch[t + w]; }
        __syncthreads();
    }
    if (t == 0) out[0] = (float)(ch[0] > 0.0 ? sh[0] / ch[0] : 0.0);
}

extern "C" void kernel_launch(void* const* d_in, const int* in_sizes, int n_in,
                              void* d_out, int out_size, void* d_ws, size_t ws_size,
                              hipStream_t stream) {
    const float* pred  = (const float*)d_in[0];
    const int* targets = (const int*)d_in[1];
    float* out         = (float*)d_out;
    const int n = in_sizes[1];     // 8192

    char* ws = (char*)d_ws;
    size_t off = 0;
    double* psum     = (double*)(ws + off); off += N_CLS * 8;
    double* pcnt     = (double*)(ws + off); off += N_CLS * 8;
    int*    bucket_g = (int*)(ws + off);    // N_CLS * n ints = 3.2 MB, fits ws

    k_gram<<<N_CLS, 512, 0, stream>>>(pred, targets, n, bucket_g, psum, pcnt);
    k_final<<<1, 128, 0, stream>>>(psum, pcnt, out);
}

// Round 7
// 74.282 us; speedup vs baseline: 1.9154x; 1.0303x over previous
//
#include <hip/hip_runtime.h>

#define N_CLS 100
#define D_DIM 256
#define MAX_M 112            // fast-path row capacity (7 tiles of 16)
#define ROW_SH 264           // shorts per LDS row = 528 B: 16B-aligned, 2-way banks (free)
#define PANEL 48             // slow-path panel rows — only if some class m > 112

typedef short bf16x8 __attribute__((ext_vector_type(8)));
typedef float f32x4  __attribute__((ext_vector_type(4)));

__device__ __forceinline__ unsigned short f2bf(float f) {   // fp32 -> bf16 RNE
    unsigned int b = __float_as_uint(f);
    return (unsigned short)((b + 0x7FFFu + ((b >> 16) & 1u)) >> 16);
}

// Stage cnt rows (class positions cp0..) into LDS slots dslot.. as bf16 + exact
// fp32 ||row||^2. Wave-per-row, lane = float4 chunk. Rows >= m stage as zeros.
__device__ __forceinline__ void stage(const float* __restrict__ pred,
        const int* bkt, int m, int cp0, int dslot, int cnt,
        short* tileS, float* sqs, int wave, int lane) {
    for (int r = wave; r < cnt; r += 8) {
        int cp = cp0 + r;
        float4 v = make_float4(0.f, 0.f, 0.f, 0.f);
        if (cp < m) {                                  // wave-uniform branch
            int g = bkt[cp];                           // wave-uniform load (LDS fast path)
            v = ((const float4*)(pred + (size_t)g * D_DIM))[lane];
        }
        short4 pk;
        pk.x = (short)f2bf(v.x); pk.y = (short)f2bf(v.y);
        pk.z = (short)f2bf(v.z); pk.w = (short)f2bf(v.w);
        *(short4*)&tileS[(dslot + r) * ROW_SH + lane * 4] = pk;
        float s = v.x * v.x + v.y * v.y + v.z * v.z + v.w * v.w;
        #pragma unroll
        for (int o = 32; o; o >>= 1) s += __shfl_xor(s, o, 64);
        if (lane == 0) sqs[dslot + r] = s;
    }
}

// One 16x16 MFMA tile. C/D layout (HW-verified): col=lane&15 -> B row,
// row=(lane>>4)*4+rr -> A row. d2 = sq_i + sq_j - 2*G_ij (sq exact fp32).
__device__ __forceinline__ float tile16(const short* tileS, const float* sqs,
        int a0, int b0, int ga0, int gb0, int m, int lane) {
    const int q = lane >> 4, l15 = lane & 15;
    const short* aP = &tileS[(a0 + l15) * ROW_SH + q * 8];
    const short* bP = &tileS[(b0 + l15) * ROW_SH + q * 8];
    f32x4 acc = {0.f, 0.f, 0.f, 0.f};
    #pragma unroll
    for (int ks = 0; ks < 8; ++ks) {
        bf16x8 af = *(const bf16x8*)(aP + ks * 32);
        bf16x8 bg = *(const bf16x8*)(bP + ks * 32);
        acc = __builtin_amdgcn_mfma_f32_16x16x32_bf16(af, bg, acc, 0, 0, 0);
    }
    float out = 0.f;
    #pragma unroll
    for (int rr = 0; rr < 4; ++rr) {
        int al = q * 4 + rr;
        int pi = ga0 + al, pj = gb0 + l15;
        float d2 = sqs[a0 + al] + sqs[b0 + l15] - 2.f * acc[rr];
        if (pj < m && pi < pj) out += sqrtf(fmaxf(d2, 0.f));
    }
    return out;
}

// ---------- Single kernel: block-per-class Gram + block-0 finalize ----------
// Ready protocol: pcnt[c] >= 0.0 always; 0xAA ws poison has sign bit set, so
// "sign clear" <=> published this call (harness re-poisons ws every launch).
// Only block 0 waits; all other blocks are independent -> no deadlock.
__global__ __launch_bounds__(512) void k_gram(const float* __restrict__ pred,
        const int* __restrict__ targets, int n, int* __restrict__ bucket_g,
        double* __restrict__ psum, double* __restrict__ pcnt, float* __restrict__ out) {
    __shared__ short tileS[MAX_M * ROW_SH];   // 59136 B
    __shared__ float sqs[MAX_M];
    __shared__ float wsum[8];
    __shared__ int bkt_s[MAX_M];
    __shared__ int cnt_s;
    const int t = threadIdx.x, lane = t & 63, wave = t >> 6;
    const int c = blockIdx.x;
    int* bkt_g = bucket_g + (size_t)c * n;    // private per-class region (fallback only)

    if (t == 0) cnt_s = 0;
    __syncthreads();
    for (int i = t; i < n; i += 512)
        if (targets[i] == c) {
            int pos = atomicAdd(&cnt_s, 1);   // order within class irrelevant
            if (pos < MAX_M) bkt_s[pos] = i;
            bkt_g[pos] = i;
        }
    __syncthreads();
    const int m = cnt_s;
    float accum = 0.f;

    if (m <= MAX_M) {
        const int T = (m + 15) >> 4;          // 0 if m==0
        stage(pred, bkt_s, m, 0, 0, T * 16, tileS, sqs, wave, lane);
        __syncthreads();
        const int np = T * (T + 1) / 2;
        for (int idx = wave; idx < np; idx += 8) {
            int ta = 0, r = idx;
            while (r >= T - ta) { r -= T - ta; ++ta; }
            int tb = ta + r;
            accum += tile16(tileS, sqs, ta * 16, tb * 16, ta * 16, tb * 16, m, lane);
        }
    } else {
        // general fallback: 48-row panel pairs (correct for any m; ~never runs)
        const int P = (m + PANEL - 1) / PANEL;
        for (int pi = 0; pi < P; ++pi)
        for (int pj = pi; pj < P; ++pj) {
            __syncthreads();
            stage(pred, bkt_g, m, pi * PANEL, 0,     PANEL, tileS, sqs, wave, lane);
            stage(pred, bkt_g, m, pj * PANEL, PANEL, PANEL, tileS, sqs, wave, lane);
            __syncthreads();
            for (int idx = wave; idx < 9; idx += 8) {
                int ta = idx / 3, tb = idx % 3;
                accum += tile16(tileS, sqs, ta * 16, PANEL + tb * 16,
                                pi * PANEL + ta * 16, pj * PANEL + tb * 16, m, lane);
            }
        }
    }

    #pragma unroll
    for (int o = 32; o; o >>= 1) accum += __shfl_xor(accum, o, 64);
    if (lane == 0) wsum[wave] = accum;
    __syncthreads();
    if (t == 0) {
        double bs = 0.0;
        #pragma unroll
        for (int w = 0; w < 8; ++w) bs += (double)wsum[w];
        __hip_atomic_store(&psum[c], bs, __ATOMIC_RELAXED, __HIP_MEMORY_SCOPE_AGENT);
        __hip_atomic_store(&pcnt[c], (double)m * (double)(m - 1) * 0.5,
                           __ATOMIC_RELEASE, __HIP_MEMORY_SCOPE_AGENT);
    }

    if (c == 0) {
        // gather all 100 per-class partials (spin until each is published)
        double mys = 0.0, myc = 0.0;
        if (t < N_CLS) {
            unsigned long long bits;
            do {
                bits = __hip_atomic_load((const unsigned long long*)&pcnt[t],
                                         __ATOMIC_ACQUIRE, __HIP_MEMORY_SCOPE_AGENT);
            } while (bits >> 63);             // poison is negative; pcnt >= 0.0
            myc = __longlong_as_double((long long)bits);
            unsigned long long sb = __hip_atomic_load((const unsigned long long*)&psum[t],
                                         __ATOMIC_RELAXED, __HIP_MEMORY_SCOPE_AGENT);
            mys = __longlong_as_double((long long)sb);
        }
        __syncthreads();                      // staging data dead; reuse tileS
        double* red_s = (double*)tileS;
        double* red_c = red_s + 128;
        if (t < 128) { red_s[t] = (t < N_CLS) ? mys : 0.0;
                       red_c[t] = (t < N_CLS) ? myc : 0.0; }
        __syncthreads();
        for (int w = 64; w; w >>= 1) {
            if (t < w) { red_s[t] += red_s[t + w]; red_c[t] += red_c[t + w]; }
            __syncthreads();
        }
        if (t == 0) out[0] = (float)(red_c[0] > 0.0 ? red_s[0] / red_c[0] : 0.0);
    }
}

extern "C" void kernel_launch(void* const* d_in, const int* in_sizes, int n_in,
                              void* d_out, int out_size, void* d_ws, size_t ws_size,
                              hipStream_t stream) {
    const float* pred  = (const float*)d_in[0];
    const int* targets = (const int*)d_in[1];
    float* out         = (float*)d_out;
    const int n = in_sizes[1];     // 8192

    char* ws = (char*)d_ws;
    size_t off = 0;
    double* psum     = (double*)(ws + off); off += N_CLS * 8;
    double* pcnt     = (double*)(ws + off); off += N_CLS * 8;
    int*    bucket_g = (int*)(ws + off);    // N_CLS * n ints = 3.2 MB, fits ws

    k_gram<<<N_CLS, 512, 0, stream>>>(pred, targets, n, bucket_g, psum, pcnt, out);
}